// Round 7
// baseline (2169.625 us; speedup 1.0000x reference)
//
#include <hip/hip_runtime.h>
#include <hip/hip_fp16.h>
#include <stdint.h>

// HeteroscedasticSoftmax: out = mean_{s<100} softmax(logits + eps_s * exp(log_std), axis=C)
// eps reproduces jax.random.normal under the partitionable threefry scheme (verified R0-R2).
//
// R6: lane-pair split. R3-R5 showed the 19-channel-per-thread live set (~60 VGPR)
// can't get both zero-spill and occupancy. Split each pixel across 2 lanes:
// even lane c=0..9, odd lane c=10..18 + dummy(c=19: sd=0, lg=-30000 -> z=-30000,
// exp2 -> 0; threefry result multiplied by 0, control flow stays uniform).
// Softmax max/sum finished with one __shfl_xor(.,1) each (fmax/add commutative ->
// bitwise identical in both lanes). acc[10]+z[10]+temps ~45 VGPR -> (256,8)
// spill-free at 8 waves/SIMD. LDS staging [256][11] half2 = 11.3 KB/block.

#define HW     65536
#define NSAMP  100

__device__ __forceinline__ uint32_t rotl(uint32_t x, uint32_t r) {
  return __builtin_amdgcn_alignbit(x, x, 32u - r);
}

__device__ __forceinline__ void tf2x32_full(uint32_t k0, uint32_t k1,
                                            uint32_t x0, uint32_t x1,
                                            uint32_t& o0, uint32_t& o1) {
  const uint32_t k2 = k0 ^ k1 ^ 0x1BD11BDAu;
#define TFR(r) { x0 += x1; x1 = rotl(x1, r) ^ x0; }
  x0 += k0; x1 += k1;
  TFR(13u) TFR(15u) TFR(26u) TFR(6u)
  x0 += k1; x1 += k2 + 1u;
  TFR(17u) TFR(29u) TFR(16u) TFR(24u)
  x0 += k2; x1 += k0 + 2u;
  TFR(13u) TFR(15u) TFR(26u) TFR(6u)
  x0 += k0; x1 += k1 + 3u;
  TFR(17u) TFR(29u) TFR(16u) TFR(24u)
  x0 += k1; x1 += k2 + 4u;
  TFR(13u) TFR(15u) TFR(26u) TFR(6u)
  x0 += k2; x1 += k0 + 5u;
#undef TFR
  o0 = x0; o1 = x1;
}

// Hot-path threefry, x0_in = 0, returns o0^o1. Keys wave-uniform (SGPR).
__device__ __forceinline__ uint32_t tf_fold(uint32_t k0, uint32_t k1, uint32_t k2,
                                            uint32_t x1in) {
  uint32_t x0, x1;
  x1 = x1in + k1;
  x0 = k0 + x1;
  x1 = rotl(x1, 13u) ^ x0;
  x0 += x1; x1 = rotl(x1, 15u) ^ x0;
  x0 += x1; x1 = rotl(x1, 26u) ^ x0;
  x0 += x1; x1 = rotl(x1,  6u) ^ x0;
  x1 += k2 + 1u;
  x0 = x0 + k1 + x1; x1 = rotl(x1, 17u) ^ x0;
  x0 += x1; x1 = rotl(x1, 29u) ^ x0;
  x0 += x1; x1 = rotl(x1, 16u) ^ x0;
  x0 += x1; x1 = rotl(x1, 24u) ^ x0;
  x1 += k0 + 2u;
  x0 = x0 + k2 + x1; x1 = rotl(x1, 13u) ^ x0;
  x0 += x1; x1 = rotl(x1, 15u) ^ x0;
  x0 += x1; x1 = rotl(x1, 26u) ^ x0;
  x0 += x1; x1 = rotl(x1,  6u) ^ x0;
  x1 += k1 + 3u;
  x0 = x0 + k0 + x1; x1 = rotl(x1, 17u) ^ x0;
  x0 += x1; x1 = rotl(x1, 29u) ^ x0;
  x0 += x1; x1 = rotl(x1, 16u) ^ x0;
  x0 += x1; x1 = rotl(x1, 24u) ^ x0;
  x1 += k2 + 4u;
  x0 = x0 + k1 + x1; x1 = rotl(x1, 13u) ^ x0;
  x0 += x1; x1 = rotl(x1, 15u) ^ x0;
  x0 += x1; x1 = rotl(x1, 26u) ^ x0;
  x0 += x1; x1 = rotl(x1,  6u) ^ x0;
  return (x0 + k2) ^ (x1 + k0 + 5u);
}

// sqrt(2)*erfinv(u); central poly in t = log2(1-u^2) (ln2 + sqrt2 folded).
__device__ __forceinline__ float bits_to_eps(uint32_t bits) {
  const float lo = -0.99999994f;  // nextafter(-1, 0)
  float x = __uint_as_float((bits >> 9) | 0x3F800000u);
  // Addend rounds to exactly -3.0f, so u hits -1.0 at bits==0;
  // the clamp is the NaN guard (R4 lesson) - do not remove.
  float u = fmaf(x, 2.0f, -3.0f);
  u = fmaxf(u, lo);
  float t = __builtin_amdgcn_logf(fmaf(-u, u, 1.0f));  // log2(1-u^2) <= 0
  float p;
  if (t > -7.2135401f) {          // central: w = -ln2*t < 5
    float tw = t + 3.6067376f;
    p = 2.1176667e-09f;
    p = fmaf(p, tw, -3.7319753e-08f);
    p = fmaf(p, tw, -5.5262077e-07f);
    p = fmaf(p, tw, 9.9370361e-07f);
    p = fmaf(p, tw, 7.1355918e-05f);
    p = fmaf(p, tw, 5.9046852e-04f);
    p = fmaf(p, tw, -2.8386612e-03f);
    p = fmaf(p, tw, -2.4177230e-01f);
    p = fmaf(p, tw, 2.1233141e+00f);
  } else {                        // tail (~0.34% of lanes)
    float w = -0.69314718f * t;
    w = __fsqrt_rn(w) - 3.0f;
    p = -2.8314594e-04f;
    p = fmaf(p, w, 1.4276565e-04f);
    p = fmaf(p, w, 1.9082604e-03f);
    p = fmaf(p, w, -5.1950124e-03f);
    p = fmaf(p, w, 8.1168916e-03f);
    p = fmaf(p, w, -1.0779791e-02f);
    p = fmaf(p, w, 1.3348577e-02f);
    p = fmaf(p, w, 1.4165810e+00f);
    p = fmaf(p, w, 4.0064324e+00f);
  }
  return p * u;
}

__global__ void HS_keys_kernel(uint2* __restrict__ ks) {
  const int t = threadIdx.x;
  if (t < NSAMP) {
    uint32_t a, b;
    tf2x32_full(0u, 1u, 0u, (uint32_t)t, a, b);  // split of key(1)
    ks[t] = make_uint2(a, b);
  }
}

__global__ __launch_bounds__(256, 8)
void HeteroscedasticSoftmax_kernel(const float* __restrict__ in,
                                   float* __restrict__ out,
                                   const uint2* __restrict__ keys) {
  __shared__ __half2 sls[256][11];  // 10 half2 per thread, +1 pad (2-way bank alias only)

  const int t      = threadIdx.x;
  const int parity = t & 1;
  const int gp     = blockIdx.x * 128 + (t >> 1);  // global pixel [0, 524288)
  const int b_     = gp >> 16;
  const int hw     = gp & 65535;
  const int cbase  = parity * 10;                  // even: c=0..9, odd: c=10..19(dummy)

  const float L2E = 1.4426950408889634f;
  const float* pin = in + (size_t)b_ * (2 * 19 * HW) + hw;
  float acc[10];
#pragma unroll
  for (int i = 0; i < 10; ++i) {
    const int c = cbase + i;
    float lg, sd;
    if (c < 19) {
      lg = pin[c * HW] * L2E;
      sd = __expf(pin[(19 + c) * HW]) * L2E;
    } else {
      lg = -30000.0f;  // dummy: z = -30000 always, exp2 -> 0
      sd = 0.0f;
    }
    sls[t][i] = __floats2half2_rn(lg, sd);
    acc[i] = 0.0f;
  }
  __syncthreads();

  const uint32_t jb2 = ((uint32_t)(b_ * 19 + cbase) << 16) + (uint32_t)hw;

#pragma unroll 1
  for (int s = 0; s < NSAMP; ++s) {
    const uint2 kk = keys[s];
    const uint32_t k0 = __builtin_amdgcn_readfirstlane(kk.x);
    const uint32_t k1 = __builtin_amdgcn_readfirstlane(kk.y);
    const uint32_t k2 = k0 ^ k1 ^ 0x1BD11BDAu;

    float z[10];
#pragma unroll
    for (int i = 0; i < 10; ++i) {
      const uint32_t bits = tf_fold(k0, k1, k2, jb2 + ((uint32_t)i << 16));
      const float eps = bits_to_eps(bits);
      const __half2 h = sls[t][i];
      z[i] = fmaf(eps, __high2float(h), __low2float(h));  // (lg + eps*sd)*log2e
    }

    // local max tree over 10 (depth 4), then pair-combine via lane^1 swizzle
    float m0 = fmaxf(z[0], z[1]), m1 = fmaxf(z[2], z[3]);
    float m2 = fmaxf(z[4], z[5]), m3 = fmaxf(z[6], z[7]);
    float m4 = fmaxf(z[8], z[9]);
    m0 = fmaxf(m0, m1); m2 = fmaxf(m2, m3);
    m0 = fmaxf(m0, m2);
    float ml = fmaxf(m0, m4);
    const float m = fmaxf(ml, __shfl_xor(ml, 1));  // both lanes: full 20-way max

#pragma unroll
    for (int i = 0; i < 10; ++i) z[i] = __builtin_amdgcn_exp2f(z[i] - m);

    float s0 = z[0] + z[1], s1 = z[2] + z[3];
    float s2 = z[4] + z[5], s3 = z[6] + z[7];
    float s4 = z[8] + z[9];
    s0 += s1; s2 += s3;
    s0 += s2;
    float sl = s0 + s4;
    const float ssum = sl + __shfl_xor(sl, 1);     // commutative add: bitwise same both lanes
    const float r = __builtin_amdgcn_rcpf(ssum);   // ssum >= 1 (max channel contributes 1)

#pragma unroll
    for (int i = 0; i < 10; ++i) acc[i] = fmaf(z[i], r, acc[i]);
  }

  float* pout = out + (size_t)b_ * (19 * HW) + hw;
#pragma unroll
  for (int i = 0; i < 10; ++i) {
    const int c = cbase + i;
    if (c < 19) pout[c * HW] = acc[i] * 0.01f;
  }
}

extern "C" void kernel_launch(void* const* d_in, const int* in_sizes, int n_in,
                              void* d_out, int out_size, void* d_ws, size_t ws_size,
                              hipStream_t stream) {
  const float* in = (const float*)d_in[0];
  float* out = (float*)d_out;
  uint2* keys = (uint2*)d_ws;  // 800 B of scratch
  HS_keys_kernel<<<1, 128, 0, stream>>>(keys);
  // 2 threads per pixel: 4096 blocks x 256 threads = 1,048,576 lanes = 524,288 px
  HeteroscedasticSoftmax_kernel<<<4096, 256, 0, stream>>>(in, out, keys);
}

// Round 8
// 2149.492 us; speedup vs baseline: 1.0094x; 1.0094x over previous
//
#include <hip/hip_runtime.h>
#include <stdint.h>

// HeteroscedasticSoftmax: out = mean_{s<100} softmax(logits + eps_s * exp(log_std), axis=C)
// eps reproduces jax.random.normal under the partitionable threefry scheme (verified R0-R2).
//
// R7: lane-QUAD split, registers only, no LDS.
// Evidence R3-R6: time pinned ~2.15ms across occupancy 39->75%; issue-bound at
// ~57% of nominal VALU rate (~= m07's empirical 65% ceiling). Remaining slack:
// residual spill traffic + per-sample LDS reads + allocator pathology (picks
// ~live-set-minus-10 and spills). Fix: shrink live set to ~36 VGPR (5 ch/lane:
// lg[5]+sd[5]+acc[5]+z[5]) so even a 32-40 reg allocation is spill-free at
// 8 waves/SIMD, and keep lg/sd in registers (no ds_read, no f16 cvts).
// Cross-lane softmax via __shfl_xor 1,2 (DPP quad_perm), commutative ops ->
// bitwise identical in all 4 lanes. Dummy channel c=19 (sd=0, lg=-30000).

#define HW     65536
#define NSAMP  100

__device__ __forceinline__ uint32_t rotl(uint32_t x, uint32_t r) {
  return __builtin_amdgcn_alignbit(x, x, 32u - r);
}

__device__ __forceinline__ void tf2x32_full(uint32_t k0, uint32_t k1,
                                            uint32_t x0, uint32_t x1,
                                            uint32_t& o0, uint32_t& o1) {
  const uint32_t k2 = k0 ^ k1 ^ 0x1BD11BDAu;
#define TFR(r) { x0 += x1; x1 = rotl(x1, r) ^ x0; }
  x0 += k0; x1 += k1;
  TFR(13u) TFR(15u) TFR(26u) TFR(6u)
  x0 += k1; x1 += k2 + 1u;
  TFR(17u) TFR(29u) TFR(16u) TFR(24u)
  x0 += k2; x1 += k0 + 2u;
  TFR(13u) TFR(15u) TFR(26u) TFR(6u)
  x0 += k0; x1 += k1 + 3u;
  TFR(17u) TFR(29u) TFR(16u) TFR(24u)
  x0 += k1; x1 += k2 + 4u;
  TFR(13u) TFR(15u) TFR(26u) TFR(6u)
  x0 += k2; x1 += k0 + 5u;
#undef TFR
  o0 = x0; o1 = x1;
}

// Hot-path threefry, x0_in = 0, returns o0^o1. Keys wave-uniform (SGPR).
__device__ __forceinline__ uint32_t tf_fold(uint32_t k0, uint32_t k1, uint32_t k2,
                                            uint32_t x1in) {
  uint32_t x0, x1;
  x1 = x1in + k1;
  x0 = k0 + x1;
  x1 = rotl(x1, 13u) ^ x0;
  x0 += x1; x1 = rotl(x1, 15u) ^ x0;
  x0 += x1; x1 = rotl(x1, 26u) ^ x0;
  x0 += x1; x1 = rotl(x1,  6u) ^ x0;
  x1 += k2 + 1u;
  x0 = x0 + k1 + x1; x1 = rotl(x1, 17u) ^ x0;
  x0 += x1; x1 = rotl(x1, 29u) ^ x0;
  x0 += x1; x1 = rotl(x1, 16u) ^ x0;
  x0 += x1; x1 = rotl(x1, 24u) ^ x0;
  x1 += k0 + 2u;
  x0 = x0 + k2 + x1; x1 = rotl(x1, 13u) ^ x0;
  x0 += x1; x1 = rotl(x1, 15u) ^ x0;
  x0 += x1; x1 = rotl(x1, 26u) ^ x0;
  x0 += x1; x1 = rotl(x1,  6u) ^ x0;
  x1 += k1 + 3u;
  x0 = x0 + k0 + x1; x1 = rotl(x1, 17u) ^ x0;
  x0 += x1; x1 = rotl(x1, 29u) ^ x0;
  x0 += x1; x1 = rotl(x1, 16u) ^ x0;
  x0 += x1; x1 = rotl(x1, 24u) ^ x0;
  x1 += k2 + 4u;
  x0 = x0 + k1 + x1; x1 = rotl(x1, 13u) ^ x0;
  x0 += x1; x1 = rotl(x1, 15u) ^ x0;
  x0 += x1; x1 = rotl(x1, 26u) ^ x0;
  x0 += x1; x1 = rotl(x1,  6u) ^ x0;
  return (x0 + k2) ^ (x1 + k0 + 5u);
}

// sqrt(2)*erfinv(u); central poly in t = log2(1-u^2) (ln2 + sqrt2 folded).
__device__ __forceinline__ float bits_to_eps(uint32_t bits) {
  const float lo = -0.99999994f;  // nextafter(-1, 0)
  float x = __uint_as_float((bits >> 9) | 0x3F800000u);
  // Addend rounds to exactly -3.0f, so u hits -1.0 at bits==0;
  // the clamp is the NaN guard (R4 lesson) - do not remove.
  float u = fmaf(x, 2.0f, -3.0f);
  u = fmaxf(u, lo);
  float t = __builtin_amdgcn_logf(fmaf(-u, u, 1.0f));  // log2(1-u^2) <= 0
  float p;
  if (t > -7.2135401f) {          // central: w = -ln2*t < 5
    float tw = t + 3.6067376f;
    p = 2.1176667e-09f;
    p = fmaf(p, tw, -3.7319753e-08f);
    p = fmaf(p, tw, -5.5262077e-07f);
    p = fmaf(p, tw, 9.9370361e-07f);
    p = fmaf(p, tw, 7.1355918e-05f);
    p = fmaf(p, tw, 5.9046852e-04f);
    p = fmaf(p, tw, -2.8386612e-03f);
    p = fmaf(p, tw, -2.4177230e-01f);
    p = fmaf(p, tw, 2.1233141e+00f);
  } else {                        // tail (~0.34% of lanes)
    float w = -0.69314718f * t;
    w = __fsqrt_rn(w) - 3.0f;
    p = -2.8314594e-04f;
    p = fmaf(p, w, 1.4276565e-04f);
    p = fmaf(p, w, 1.9082604e-03f);
    p = fmaf(p, w, -5.1950124e-03f);
    p = fmaf(p, w, 8.1168916e-03f);
    p = fmaf(p, w, -1.0779791e-02f);
    p = fmaf(p, w, 1.3348577e-02f);
    p = fmaf(p, w, 1.4165810e+00f);
    p = fmaf(p, w, 4.0064324e+00f);
  }
  return p * u;
}

__global__ void HS_keys_kernel(uint2* __restrict__ ks) {
  const int t = threadIdx.x;
  if (t < NSAMP) {
    uint32_t a, b;
    tf2x32_full(0u, 1u, 0u, (uint32_t)t, a, b);  // split of key(1)
    ks[t] = make_uint2(a, b);
  }
}

__global__ __launch_bounds__(256, 8)
void HeteroscedasticSoftmax_kernel(const float* __restrict__ in,
                                   float* __restrict__ out,
                                   const uint2* __restrict__ keys) {
  const int t     = threadIdx.x;
  const int l4    = t & 3;                       // lane within quad
  const int gp    = blockIdx.x * 64 + (t >> 2);  // global pixel [0, 524288)
  const int b_    = gp >> 16;
  const int hw    = gp & 65535;
  const int cbase = l4 * 5;                      // 0,5,10,15; c=19 is dummy

  const float L2E = 1.4426950408889634f;
  const float* pin = in + (size_t)b_ * (2 * 19 * HW) + hw;
  float lg[5], sd[5], acc[5];
#pragma unroll
  for (int i = 0; i < 5; ++i) {
    const int c = cbase + i;
    if (c < 19) {
      lg[i] = pin[c * HW] * L2E;
      sd[i] = __expf(pin[(19 + c) * HW]) * L2E;
    } else {
      lg[i] = -30000.0f;  // dummy: z=-30000, exp2 -> 0, never stored
      sd[i] = 0.0f;
    }
    acc[i] = 0.0f;
  }

  const uint32_t jb = ((uint32_t)(b_ * 19 + cbase) << 16) + (uint32_t)hw;

#pragma unroll 1
  for (int s = 0; s < NSAMP; ++s) {
    const uint2 kk = keys[s];
    const uint32_t k0 = __builtin_amdgcn_readfirstlane(kk.x);
    const uint32_t k1 = __builtin_amdgcn_readfirstlane(kk.y);
    const uint32_t k2 = k0 ^ k1 ^ 0x1BD11BDAu;

    float z[5];
#pragma unroll
    for (int i = 0; i < 5; ++i) {
      const uint32_t bits = tf_fold(k0, k1, k2, jb + ((uint32_t)i << 16));
      z[i] = fmaf(bits_to_eps(bits), sd[i], lg[i]);
    }

    // local max over 5 (v_max3 x2), then quad-combine via DPP shuffles
    float ml = fmaxf(fmaxf(fmaxf(z[0], z[1]), z[2]), fmaxf(z[3], z[4]));
    float mp = fmaxf(ml, __shfl_xor(ml, 1));
    const float m = fmaxf(mp, __shfl_xor(mp, 2));  // full 20-way max, all 4 lanes identical

#pragma unroll
    for (int i = 0; i < 5; ++i) z[i] = __builtin_amdgcn_exp2f(z[i] - m);

    float sl = ((z[0] + z[1]) + z[2]) + (z[3] + z[4]);
    float sp = sl + __shfl_xor(sl, 1);
    const float ssum = sp + __shfl_xor(sp, 2);     // commutative -> bitwise same in quad
    const float r = __builtin_amdgcn_rcpf(ssum);   // ssum >= 1 (max channel contributes 1)

#pragma unroll
    for (int i = 0; i < 5; ++i) acc[i] = fmaf(z[i], r, acc[i]);
  }

  float* pout = out + (size_t)b_ * (19 * HW) + hw;
#pragma unroll
  for (int i = 0; i < 5; ++i) {
    const int c = cbase + i;
    if (c < 19) pout[c * HW] = acc[i] * 0.01f;
  }
}

extern "C" void kernel_launch(void* const* d_in, const int* in_sizes, int n_in,
                              void* d_out, int out_size, void* d_ws, size_t ws_size,
                              hipStream_t stream) {
  const float* in = (const float*)d_in[0];
  float* out = (float*)d_out;
  uint2* keys = (uint2*)d_ws;  // 800 B of scratch
  HS_keys_kernel<<<1, 128, 0, stream>>>(keys);
  // 4 threads per pixel: 8192 blocks x 256 threads = 2,097,152 lanes = 524,288 px
  HeteroscedasticSoftmax_kernel<<<8192, 256, 0, stream>>>(in, out, keys);
}